// Round 6
// baseline (465.134 us; speedup 1.0000x reference)
//
#include <hip/hip_runtime.h>

// ---------------------------------------------------------------------------
// Fused attention: qp = q@Wq+bq ; kp = k@Wk+bk ; vp = v@Wv+bv
// S = qp kp^T / 16 ; A = softmax(S) ; A = where(threefry_mask, A/0.8, 0)
// out = A vp.   B=4, L=4096, D=256, DV=64.  fp32 in/out, bf16 MFMA internally.
//
// R5: KSPLIT=8 (grid 2048, 6 blocks/CU resident), bf16 partO, threefry fused
// into exp loop (no bitmask), Wq/bq pre-scaled by log2e/16, vp row-major with
// attn-side LDS transpose, N-split projections (4 waves/SIMD).
// ---------------------------------------------------------------------------

typedef short s16x8 __attribute__((ext_vector_type(8)));   // 8 bf16 (4 VGPR)
typedef short s16x4 __attribute__((ext_vector_type(4)));
typedef float f32x4 __attribute__((ext_vector_type(4)));

#define L    4096
#define DM   256
#define DV   64
#define MTOT 16384            // B*L rows
#define KSPLIT 8
#define KBLK 32               // keys per LDS tile
#define CEXP 0.09016844005556021f   // log2(e)/16

__device__ __forceinline__ short f2bf(float f) {           // RNE fp32->bf16
  unsigned u = __builtin_bit_cast(unsigned, f);
  u += 0x7FFFu + ((u >> 16) & 1u);
  return (short)(u >> 16);
}
__device__ __forceinline__ float bf2f(short s) {
  unsigned u = ((unsigned)(unsigned short)s) << 16;
  return __builtin_bit_cast(float, u);
}
__device__ __forceinline__ unsigned rotl32c(unsigned x, int r) {
  return (x << r) | (x >> (32 - r));                       // -> v_alignbit_b32
}

// JAX partitionable threefry2x32, key=(0,42), counter=(0,ctr). Returns the
// output bits x0^x1; keep iff bits < 0.8*2^32 (bit-exact, verified R1).
__device__ __forceinline__ unsigned tf_bits(unsigned ctr) {
  unsigned x0 = 0u;
  unsigned x1 = ctr + 42u;
#define TFR(r) { x0 += x1; x1 = rotl32c(x1, r); x1 ^= x0; }
  TFR(13) TFR(15) TFR(26) TFR(6)
  x0 += 42u;          x1 += 0x1BD11BF1u;                   // ks2=0x1BD11BDA^42, +1
  TFR(17) TFR(29) TFR(16) TFR(24)
  x0 += 0x1BD11BF0u;  x1 += 2u;
  TFR(13) TFR(15) TFR(26) TFR(6)
  /* x0 += 0 */       x1 += 45u;                           // 42 + 3
  TFR(17) TFR(29) TFR(16) TFR(24)
  x0 += 42u;          x1 += 0x1BD11BF4u;                   // ks2 + 4
  TFR(13) TFR(15) TFR(26) TFR(6)
  x0 += 0x1BD11BF0u;  x1 += 5u;
#undef TFR
  return x0 ^ x1;
}

// ---------------------------------------------------------------------------
// Prep: W -> W^T bf16 (contiguous B-fragments); Wq/bq pre-scaled by log2e/16
// so attn can use exp2f(score) with no multiply.
// ---------------------------------------------------------------------------
__global__ __launch_bounds__(256) void prep_kernel(
    const float* __restrict__ Wq, const float* __restrict__ bq,
    const float* __restrict__ Wk, const float* __restrict__ Wv,
    short* __restrict__ wqT, short* __restrict__ wkT,
    short* __restrict__ wvT, float* __restrict__ bqs) {
  const int idx = blockIdx.x * 256 + threadIdx.x;
  if (idx < 65536) {                       // Wq 256x256 -> wqT[n*256+k], scaled
    const int n = idx >> 8, k = idx & 255;
    wqT[idx] = f2bf(Wq[k * 256 + n] * CEXP);
  }
  if (idx < 8192) {                        // Wk 32x256 -> wkT[n*32+k]
    const int n = idx >> 5, k = idx & 31;
    wkT[idx] = f2bf(Wk[k * 256 + n]);
  }
  if (idx < 16384) {                       // Wv 256x64 -> wvT[n*256+k]
    const int n = idx >> 8, k = idx & 255;
    wvT[idx] = f2bf(Wv[k * 64 + n]);
  }
  if (idx < 256) bqs[idx] = bq[idx] * CEXP;
}

// ---------------------------------------------------------------------------
// Projection: out[M,NOUT](bf16) = A[M,K](f32) @ W + bias, W^T bf16 given.
// Block = 4 waves x 16 rows x 64 cols (NT=4); grid.y = NOUT/64 col-splits.
// MFMA 16x16x32 frags: A/B lane (l&15)=m/n, k=(l>>4)*8+j ; C row=(l>>4)*4+j,
// col=l&15.
// ---------------------------------------------------------------------------
template <int K, int NOUT>
__global__ __launch_bounds__(256) void proj_kernel(
    const float* __restrict__ A, const short* __restrict__ WT,
    const float* __restrict__ bias, short* __restrict__ out) {
  const int lane = threadIdx.x & 63;
  const int wv   = threadIdx.x >> 6;
  const int l15 = lane & 15, l4 = lane >> 4;
  const int rowbase = blockIdx.x * 64 + wv * 16;
  const int ncol0 = blockIdx.y * 64;
  f32x4 acc[4];
#pragma unroll
  for (int i = 0; i < 4; ++i) acc[i] = (f32x4){0.f, 0.f, 0.f, 0.f};
  const int arow = rowbase + l15;
#pragma unroll
  for (int kc = 0; kc < K / 32; ++kc) {
    const f32x4* ap = (const f32x4*)(A + (size_t)arow * K + kc * 32 + l4 * 8);
    f32x4 a0 = ap[0], a1 = ap[1];
    s16x8 af;
#pragma unroll
    for (int j = 0; j < 4; ++j) { af[j] = f2bf(a0[j]); af[4 + j] = f2bf(a1[j]); }
#pragma unroll
    for (int nt = 0; nt < 4; ++nt) {
      const s16x8 bf = *(const s16x8*)(WT + (size_t)(ncol0 + nt * 16 + l15) * K + kc * 32 + l4 * 8);
      acc[nt] = __builtin_amdgcn_mfma_f32_16x16x32_bf16(af, bf, acc[nt], 0, 0, 0);
    }
  }
#pragma unroll
  for (int nt = 0; nt < 4; ++nt) {
    const int gcol = ncol0 + nt * 16 + l15;
    const float bv = bias[gcol];
#pragma unroll
    for (int j = 0; j < 4; ++j) {
      const int grow = rowbase + l4 * 4 + j;
      out[(size_t)grow * NOUT + gcol] = f2bf(acc[nt][j] + bv);
    }
  }
}

// ---------------------------------------------------------------------------
// Fused flash attention + exact-threefry dropout, split-K (z = 1/8 of keys).
// Block: 256 thr (4 waves), 64 q-rows (16/wave), 16 iters of 32 keys.
// kbuf [32][256] bf16 swz ^(l15&7)<<3 ; vbuf V^T [64dv][32k] swz ^(dv&3)<<3
// (transposed at staging from row-major vp) ; pbuf per-wave [16][32].
// Emits partial O (bf16) and partial Z (f32).
// ---------------------------------------------------------------------------
__global__ __launch_bounds__(256, 6) void attn_kernel(
    const short* __restrict__ qp, const short* __restrict__ kp,
    const short* __restrict__ vp, short* __restrict__ partO,
    float* __restrict__ partZ) {
  __shared__ __align__(16) short kbuf[KBLK * 256];   // 16 KB
  __shared__ __align__(16) short vbuf[DV * KBLK];    // 4 KB
  __shared__ __align__(16) short pbuf[4][16 * KBLK]; // 4 KB
  const int tid = threadIdx.x;
  const int lane = tid & 63, wv = tid >> 6;
  const int l15 = lane & 15, l4 = lane >> 4;
  const int qt = blockIdx.x, b = blockIdx.y, z = blockIdx.z;
  const int qrow0 = b * L + qt * 64 + wv * 16;  // global row in [MTOT] space

  // Q fragments in registers (Wq pre-scaled by log2e/16)
  s16x8 qf[8];
#pragma unroll
  for (int kc = 0; kc < 8; ++kc)
    qf[kc] = *(const s16x8*)(qp + (size_t)(qrow0 + l15) * DM + kc * 32 + l4 * 8);

  f32x4 accO[4];
#pragma unroll
  for (int i = 0; i < 4; ++i) accO[i] = (f32x4){0.f, 0.f, 0.f, 0.f};
  float zpart[4] = {0.f, 0.f, 0.f, 0.f};

  const unsigned qglob = (unsigned)qrow0;
  // V staging decomposition (constant per thread)
  const int vkey = tid & 31, vdv0 = (tid >> 5) * 8;

  for (int i = 0; i < L / KSPLIT / KBLK; ++i) {
    const int kbase = (z * (L / KSPLIT / KBLK) + i) * KBLK;
    __syncthreads();
    {  // stage K tile: 32 rows x 512B, swizzle elem ^= (row&7)<<3
      const short* src = kp + (size_t)(b * L + kbase) * DM;
#pragma unroll
      for (int it = 0; it < 4; ++it) {
        const int c = it * 256 + tid;
        const int row = c >> 5, off = (c & 31) * 8;
        const int e = (row * 256 + off) ^ ((row & 7) << 3);
        *(s16x8*)(kbuf + e) = *(const s16x8*)(src + (size_t)row * DM + off);
      }
      // stage V tile transposed: vp[key][dv] (row-major) -> vbuf[dv][key^swz]
      const s16x8 vv = *(const s16x8*)(vp + (size_t)(b * L + kbase + vkey) * DV + vdv0);
#pragma unroll
      for (int m = 0; m < 8; ++m) {
        const int dv = vdv0 + m;
        vbuf[dv * KBLK + (vkey ^ ((dv & 3) << 3))] = vv[m];
      }
    }
    __syncthreads();

    // ---- QK^T: 2 key-tiles x 8 k-chunks ----
    f32x4 sf[2];
#pragma unroll
    for (int kt = 0; kt < 2; ++kt) sf[kt] = (f32x4){0.f, 0.f, 0.f, 0.f};
#pragma unroll
    for (int kc = 0; kc < 8; ++kc) {
#pragma unroll
      for (int kt = 0; kt < 2; ++kt) {
        const int row = kt * 16 + l15;
        const int e = (row * 256 + kc * 32 + l4 * 8) ^ ((row & 7) << 3);
        const s16x8 kf = *(const s16x8*)(kbuf + e);
        sf[kt] = __builtin_amdgcn_mfma_f32_16x16x32_bf16(qf[kc], kf, sf[kt], 0, 0, 0);
      }
    }

    // ---- exp + fused threefry dropout + Z + masked P into pbuf ----
#pragma unroll
    for (int kt = 0; kt < 2; ++kt) {
#pragma unroll
      for (int j = 0; j < 4; ++j) {
        const float e = exp2f(sf[kt][j]);
        zpart[j] += e;
        const unsigned idx = ((qglob + (unsigned)(l4 * 4 + j)) << 12) +
                             (unsigned)(kbase + kt * 16 + l15);
        const float pd = (tf_bits(idx) < 3435974144u) ? e : 0.0f;
        const int row = l4 * 4 + j, col = kt * 16 + l15;
        pbuf[wv][(row * KBLK + col) ^ ((row & 3) << 3)] = f2bf(pd);
      }
    }
    // pbuf is per-wave (same-wave write->read ordered by lgkmcnt); barrier
    // protects kbuf/vbuf reuse next iteration.
    __syncthreads();

    // ---- PV: P[16x32] @ V[32x64] ----
    {
      const int pe = (l15 * KBLK + l4 * 8) ^ ((l15 & 3) << 3);
      const s16x8 pa = *(const s16x8*)(&pbuf[wv][0] + pe);
#pragma unroll
      for (int nt = 0; nt < 4; ++nt) {
        const int vrow = nt * 16 + l15;
        const int ve = (vrow * KBLK + l4 * 8) ^ ((vrow & 3) << 3);
        const s16x8 vb = *(const s16x8*)(vbuf + ve);
        accO[nt] = __builtin_amdgcn_mfma_f32_16x16x32_bf16(pa, vb, accO[nt], 0, 0, 0);
      }
    }
  }

  // ---- epilogue: reduce Z across 16-lane group, store bf16 partials ----
#pragma unroll
  for (int j = 0; j < 4; ++j) {
    float zf = zpart[j];
    zf += __shfl_xor(zf, 1);
    zf += __shfl_xor(zf, 2);
    zf += __shfl_xor(zf, 4);
    zf += __shfl_xor(zf, 8);
    const int grow = qrow0 + l4 * 4 + j;
    if (l15 == 0) partZ[(size_t)z * MTOT + grow] = zf;
#pragma unroll
    for (int nt = 0; nt < 4; ++nt)
      partO[((size_t)z * MTOT + grow) * DV + nt * 16 + l15] = f2bf(accO[nt][j]);
  }
}

// ---------------------------------------------------------------------------
// Combine: out[row][dv] = sum_z O / (0.8 * sum_z Z[row]).  4 f32 per thread.
// ---------------------------------------------------------------------------
__global__ __launch_bounds__(256) void combine_kernel(
    const short* __restrict__ partO, const float* __restrict__ partZ,
    float* __restrict__ out) {
  const int i = blockIdx.x * 256 + threadIdx.x;  // groups of 4 f32
  const int row = i >> 4, col0 = (i & 15) * 4;
  f32x4 acc = (f32x4){0.f, 0.f, 0.f, 0.f};
  float zf = 0.f;
#pragma unroll
  for (int z = 0; z < KSPLIT; ++z) {
    const s16x4 p = *(const s16x4*)(partO + (((size_t)z * MTOT + row) << 6) + col0);
#pragma unroll
    for (int m = 0; m < 4; ++m) acc[m] += bf2f(p[m]);
    zf += partZ[(size_t)z * MTOT + row];
  }
  const float inv = 1.0f / (0.8f * zf);
  *(f32x4*)(out + (size_t)i * 4) = acc * inv;
}

// ---------------------------------------------------------------------------
extern "C" void kernel_launch(void* const* d_in, const int* in_sizes, int n_in,
                              void* d_out, int out_size, void* d_ws, size_t ws_size,
                              hipStream_t stream) {
  const float* q  = (const float*)d_in[0];
  const float* k  = (const float*)d_in[1];
  const float* v  = (const float*)d_in[2];
  const float* Wq = (const float*)d_in[3];
  const float* bq = (const float*)d_in[4];
  const float* Wk = (const float*)d_in[5];
  const float* bk = (const float*)d_in[6];
  const float* Wv = (const float*)d_in[7];
  const float* bv = (const float*)d_in[8];
  float* out = (float*)d_out;

  // ws layout: qp 8.4 | kp 8.4 | vp 2.1 | partO(bf16) 16.8 | partZ 0.52
  //            | wqT/wkT/wvT/bqs ~0.2   (total ~36.4 MB)
  short* qp  = (short*)d_ws;
  short* kpb = qp + (size_t)MTOT * DM;
  short* vp  = kpb + (size_t)MTOT * DM;
  short* partO = vp + (size_t)MTOT * DV;
  float* partZ = (float*)(partO + (size_t)KSPLIT * MTOT * DV);
  short* wqT = (short*)(partZ + (size_t)KSPLIT * MTOT);
  short* wkT = wqT + 256 * 256;
  short* wvT = wkT + 32 * 256;
  float* bqs = (float*)(wvT + 64 * 256);

  prep_kernel<<<256, 256, 0, stream>>>(Wq, bq, Wk, Wv, wqT, wkT, wvT, bqs);
  proj_kernel<256, 256><<<dim3(MTOT / 64, 4), 256, 0, stream>>>(q, wqT, bqs, qp);
  proj_kernel<32, 256><<<dim3(MTOT / 64, 4), 256, 0, stream>>>(k, wkT, bk, kpb);
  proj_kernel<256, 64><<<dim3(MTOT / 64, 1), 256, 0, stream>>>(v, wvT, bv, vp);
  attn_kernel<<<dim3(64, 4, KSPLIT), 256, 0, stream>>>(qp, kpb, vp, partO, partZ);
  combine_kernel<<<MTOT * DV / 1024, 256, 0, stream>>>(partO, partZ, out);
}

// Round 7
// 424.399 us; speedup vs baseline: 1.0960x; 1.0960x over previous
//
#include <hip/hip_runtime.h>

// ---------------------------------------------------------------------------
// Fused attention: qp = q@Wq+bq ; kp = k@Wk+bk ; vp = v@Wv+bv
// S = qp kp^T / 16 ; A = softmax(S) ; A = where(threefry_mask, A/0.8, 0)
// out = A vp.   B=4, L=4096, D=256, DV=64.  fp32 in/out, bf16 MFMA internally.
//
// R6: XCD-aware swizzle (per-XCD K slice L2-resident; fixes R5's 538MB fetch),
// KBLK=64 (R1's cheaper per-key VALU), V direct from global vpT (no vbuf, no
// V-staging), coalesced partO epilogue via LDS bounce, single fused
// projection launch producing qp/kp/vpT.
// ---------------------------------------------------------------------------

typedef short s16x8 __attribute__((ext_vector_type(8)));   // 8 bf16 (4 VGPR)
typedef short s16x4 __attribute__((ext_vector_type(4)));
typedef float f32x4 __attribute__((ext_vector_type(4)));

#define L    4096
#define DM   256
#define DV   64
#define MTOT 16384            // B*L rows
#define KSPLIT 8
#define KBLK 64               // keys per tile
#define CEXP 0.09016844005556021f   // log2(e)/16

__device__ __forceinline__ short f2bf(float f) {           // RNE fp32->bf16
  unsigned u = __builtin_bit_cast(unsigned, f);
  u += 0x7FFFu + ((u >> 16) & 1u);
  return (short)(u >> 16);
}
__device__ __forceinline__ float bf2f(short s) {
  unsigned u = ((unsigned)(unsigned short)s) << 16;
  return __builtin_bit_cast(float, u);
}
__device__ __forceinline__ unsigned rotl32c(unsigned x, int r) {
  return (x << r) | (x >> (32 - r));
}

// JAX partitionable threefry2x32, key=(0,42), counter=(0,ctr). Returns
// x0^x1; keep iff bits < 0.8*2^32 (bit-exact, verified R1).
__device__ __forceinline__ unsigned tf_bits(unsigned ctr) {
  unsigned x0 = 0u;
  unsigned x1 = ctr + 42u;
#define TFR(r) { x0 += x1; x1 = rotl32c(x1, r); x1 ^= x0; }
  TFR(13) TFR(15) TFR(26) TFR(6)
  x0 += 42u;          x1 += 0x1BD11BF1u;                   // ks2=0x1BD11BDA^42, +1
  TFR(17) TFR(29) TFR(16) TFR(24)
  x0 += 0x1BD11BF0u;  x1 += 2u;
  TFR(13) TFR(15) TFR(26) TFR(6)
  /* x0 += 0 */       x1 += 45u;                           // 42 + 3
  TFR(17) TFR(29) TFR(16) TFR(24)
  x0 += 42u;          x1 += 0x1BD11BF4u;                   // ks2 + 4
  TFR(13) TFR(15) TFR(26) TFR(6)
  x0 += 0x1BD11BF0u;  x1 += 5u;
#undef TFR
  return x0 ^ x1;
}

// ---------------------------------------------------------------------------
// Prep: W -> W^T bf16; Wq/bq pre-scaled by log2e/16.
// ---------------------------------------------------------------------------
__global__ __launch_bounds__(256) void prep_kernel(
    const float* __restrict__ Wq, const float* __restrict__ bq,
    const float* __restrict__ Wk, const float* __restrict__ Wv,
    short* __restrict__ wqT, short* __restrict__ wkT,
    short* __restrict__ wvT, float* __restrict__ bqs) {
  const int idx = blockIdx.x * 256 + threadIdx.x;
  if (idx < 65536) {                       // Wq 256x256 -> wqT[n*256+k], scaled
    const int n = idx >> 8, k = idx & 255;
    wqT[idx] = f2bf(Wq[k * 256 + n] * CEXP);
  }
  if (idx < 8192) {                        // Wk 32x256 -> wkT[n*32+k]
    const int n = idx >> 5, k = idx & 31;
    wkT[idx] = f2bf(Wk[k * 256 + n]);
  }
  if (idx < 16384) {                       // Wv 256x64 -> wvT[n*256+k]
    const int n = idx >> 8, k = idx & 255;
    wvT[idx] = f2bf(Wv[k * 64 + n]);
  }
  if (idx < 256) bqs[idx] = bq[idx] * CEXP;
}

// ---------------------------------------------------------------------------
// Shared projection body: acc[nt] = A[rows 16/wave] @ W (W^T bf16 given).
// MFMA 16x16x32 frags: A/B lane (l&15)=m/n, k=(l>>4)*8+j ; C row=(l>>4)*4+j,
// col=l&15.
// ---------------------------------------------------------------------------
template <int K>
__device__ __forceinline__ void proj_acc(
    const float* __restrict__ A, const short* __restrict__ WT,
    int arow, int ncol0, int l15, int l4, f32x4 acc[4]) {
#pragma unroll
  for (int kc = 0; kc < K / 32; ++kc) {
    const f32x4* ap = (const f32x4*)(A + (size_t)arow * K + kc * 32 + l4 * 8);
    f32x4 a0 = ap[0], a1 = ap[1];
    s16x8 af;
#pragma unroll
    for (int j = 0; j < 4; ++j) { af[j] = f2bf(a0[j]); af[4 + j] = f2bf(a1[j]); }
#pragma unroll
    for (int nt = 0; nt < 4; ++nt) {
      const s16x8 bf = *(const s16x8*)(WT + (size_t)(ncol0 + nt * 16 + l15) * K + kc * 32 + l4 * 8);
      acc[nt] = __builtin_amdgcn_mfma_f32_16x16x32_bf16(af, bf, acc[nt], 0, 0, 0);
    }
  }
}

// ---------------------------------------------------------------------------
// Fused projections, one launch:
//  blocks [0,1024):   qp[row][n] ;  rb=part&255, nc0=(part>>8)*64
//  blocks [1024,2048): kp[row][n]
//  blocks [2048,2304): vpT[b*64+dv][key] via LDS transpose (64 rows x 64 dv)
// ---------------------------------------------------------------------------
__global__ __launch_bounds__(256) void proj_all_kernel(
    const float* __restrict__ q, const float* __restrict__ k,
    const float* __restrict__ v, const short* __restrict__ wqT,
    const short* __restrict__ wkT, const short* __restrict__ wvT,
    const float* __restrict__ bqs, const float* __restrict__ bk,
    const float* __restrict__ bv, short* __restrict__ qp,
    short* __restrict__ kpb, short* __restrict__ vpT) {
  __shared__ __align__(16) short tbuf[64 * 64];  // v transpose tile, 8 KB
  const int part = blockIdx.x;
  const int tid = threadIdx.x;
  const int lane = tid & 63, wv = tid >> 6;
  const int l15 = lane & 15, l4 = lane >> 4;
  f32x4 acc[4];
#pragma unroll
  for (int i = 0; i < 4; ++i) acc[i] = (f32x4){0.f, 0.f, 0.f, 0.f};

  if (part < 2048) {
    const bool isq = part < 1024;
    const int p = isq ? part : part - 1024;
    const int rowbase = (p & 255) * 64 + wv * 16;
    const int nc0 = (p >> 8) * 64;
    if (isq) proj_acc<256>(q, wqT, rowbase + l15, nc0, l15, l4, acc);
    else     proj_acc<32>(k, wkT, rowbase + l15, nc0, l15, l4, acc);
    const float* bias = isq ? bqs : bk;
    short* out = isq ? qp : kpb;
#pragma unroll
    for (int nt = 0; nt < 4; ++nt) {
      const float bb = bias[nc0 + nt * 16 + l15];
#pragma unroll
      for (int j = 0; j < 4; ++j)
        out[(size_t)(rowbase + l4 * 4 + j) * DM + nc0 + nt * 16 + l15] =
            f2bf(acc[nt][j] + bb);
    }
  } else {
    // ---- v-projection with transposed output ----
    const int p = part - 2048;                 // 0..255
    const int rowbase0 = p * 64;               // global key-row base
    const int rowbase = rowbase0 + wv * 16;
    proj_acc<256>(v, wvT, rowbase + l15, 0, l15, l4, acc);
#pragma unroll
    for (int nt = 0; nt < 4; ++nt) {
      const float bb = bv[nt * 16 + l15];
#pragma unroll
      for (int j = 0; j < 4; ++j)             // tbuf[dv][key_local]
        tbuf[(nt * 16 + l15) * 64 + (wv * 16 + l4 * 4 + j)] = f2bf(acc[nt][j] + bb);
    }
    __syncthreads();
    const int b = rowbase0 >> 12, key0 = rowbase0 & 4095;
#pragma unroll
    for (int it = 0; it < 2; ++it) {          // 512 8-key chunks / 256 thr
      const int c = it * 256 + tid;
      const int dv = c & 63, k8 = (c >> 6) * 8;
      *(s16x8*)(vpT + (size_t)(b * 64 + dv) * L + key0 + k8) =
          *(const s16x8*)(tbuf + dv * 64 + k8);
    }
  }
}

// ---------------------------------------------------------------------------
// Fused flash attention + exact-threefry dropout, split-K, XCD-swizzled.
// 1-D grid 2048; swz=(wg&7)*256+(wg>>3) -> XCD r owns z-slice r (all b, qt):
// per-XCD K working set = 4 x 256KB, L2-resident.
// Block: 256 thr (4 waves), 64 q-rows, 8 iters of 64 keys.
// kbuf [64][256] swz ^(row&7)<<3 ; pbuf per-wave [16][64] ^(row&7)<<3 ;
// V read directly from global vpT (L2-hot). Emits bf16 partO + f32 partZ.
// ---------------------------------------------------------------------------
__global__ __launch_bounds__(256, 4) void attn_kernel(
    const short* __restrict__ qp, const short* __restrict__ kp,
    const short* __restrict__ vpT, short* __restrict__ partO,
    float* __restrict__ partZ) {
  __shared__ __align__(16) short kbuf[KBLK * 256];   // 32 KB
  __shared__ __align__(16) short pbuf[4][16 * KBLK]; // 8 KB
  const int tid = threadIdx.x;
  const int lane = tid & 63, wv = tid >> 6;
  const int l15 = lane & 15, l4 = lane >> 4;
  const int wg = blockIdx.x;
  const int swz = (wg & 7) * 256 + (wg >> 3);
  const int qt = swz & 63, g = swz >> 6;
  const int b = g & 3, z = g >> 2;
  const int qrow0 = b * L + qt * 64 + wv * 16;  // global row in [MTOT]

  s16x8 qf[8];                                  // Q frags (Wq pre-scaled)
#pragma unroll
  for (int kc = 0; kc < 8; ++kc)
    qf[kc] = *(const s16x8*)(qp + (size_t)(qrow0 + l15) * DM + kc * 32 + l4 * 8);

  f32x4 accO[4];
#pragma unroll
  for (int i = 0; i < 4; ++i) accO[i] = (f32x4){0.f, 0.f, 0.f, 0.f};
  float zpart[4] = {0.f, 0.f, 0.f, 0.f};
  const unsigned qglob = (unsigned)qrow0;

  for (int i = 0; i < L / KSPLIT / KBLK; ++i) {   // 8 iterations
    const int kbase = (z * (L / KSPLIT) ) + i * KBLK;
    __syncthreads();
    {  // stage K tile: 64 rows x 512B, swizzle elem ^= (row&7)<<3
      const short* src = kp + (size_t)(b * L + kbase) * DM;
#pragma unroll
      for (int it = 0; it < 8; ++it) {
        const int c = it * 256 + tid;
        const int row = c >> 5, off = (c & 31) * 8;
        const int e = (row * 256 + off) ^ ((row & 7) << 3);
        *(s16x8*)(kbuf + e) = *(const s16x8*)(src + (size_t)row * DM + off);
      }
    }
    __syncthreads();

    // ---- QK^T: 4 key-tiles x 8 k-chunks ----
    f32x4 sf[4];
#pragma unroll
    for (int kt = 0; kt < 4; ++kt) sf[kt] = (f32x4){0.f, 0.f, 0.f, 0.f};
#pragma unroll
    for (int kc = 0; kc < 8; ++kc) {
#pragma unroll
      for (int kt = 0; kt < 4; ++kt) {
        const int row = kt * 16 + l15;
        const int e = (row * 256 + kc * 32 + l4 * 8) ^ ((row & 7) << 3);
        const s16x8 kf = *(const s16x8*)(kbuf + e);
        sf[kt] = __builtin_amdgcn_mfma_f32_16x16x32_bf16(qf[kc], kf, sf[kt], 0, 0, 0);
      }
    }

    // ---- exp + fused threefry dropout + Z + masked P into pbuf ----
#pragma unroll
    for (int kt = 0; kt < 4; ++kt) {
#pragma unroll
      for (int j = 0; j < 4; ++j) {
        const float e = exp2f(sf[kt][j]);
        zpart[j] += e;
        const unsigned idx = ((qglob + (unsigned)(l4 * 4 + j)) << 12) +
                             (unsigned)(kbase + kt * 16 + l15);
        const float pd = (tf_bits(idx) < 3435974144u) ? e : 0.0f;
        const int row = l4 * 4 + j, col = kt * 16 + l15;
        pbuf[wv][(row * KBLK + col) ^ ((row & 7) << 3)] = f2bf(pd);
      }
    }
    // pbuf per-wave: same-wave write->read ordered by lgkmcnt; no barrier.

    // ---- PV: P[16x64] @ V[64x64], V frags direct from global vpT ----
#pragma unroll
    for (int ks = 0; ks < 2; ++ks) {
      const int pe = (l15 * KBLK + ks * 32 + l4 * 8) ^ ((l15 & 7) << 3);
      const s16x8 pa = *(const s16x8*)(&pbuf[wv][0] + pe);
#pragma unroll
      for (int nt = 0; nt < 4; ++nt) {
        const s16x8 vb = *(const s16x8*)(
            vpT + (size_t)(b * 64 + nt * 16 + l15) * L + kbase + ks * 32 + l4 * 8);
        accO[nt] = __builtin_amdgcn_mfma_f32_16x16x32_bf16(pa, vb, accO[nt], 0, 0, 0);
      }
    }
  }

  // ---- epilogue: Z reduce + coalesced partO via LDS bounce ----
#pragma unroll
  for (int j = 0; j < 4; ++j) {
    float zf = zpart[j];
    zf += __shfl_xor(zf, 1);
    zf += __shfl_xor(zf, 2);
    zf += __shfl_xor(zf, 4);
    zf += __shfl_xor(zf, 8);
    if (l15 == 0) partZ[(size_t)z * MTOT + qrow0 + l4 * 4 + j] = zf;
  }
  __syncthreads();                       // all waves done reading kbuf
  float* fb = (float*)kbuf + wv * 1024;  // 16x64 f32 per wave
#pragma unroll
  for (int nt = 0; nt < 4; ++nt)
#pragma unroll
    for (int j = 0; j < 4; ++j)
      fb[(l4 * 4 + j) * 64 + nt * 16 + l15] = accO[nt][j];
  // same-wave read (lgkmcnt-ordered)
  const int r = lane >> 2, c0 = (lane & 3) * 16;
  s16x8 o0, o1;
#pragma unroll
  for (int m = 0; m < 8; ++m) o0[m] = f2bf(fb[r * 64 + c0 + m]);
#pragma unroll
  for (int m = 0; m < 8; ++m) o1[m] = f2bf(fb[r * 64 + c0 + 8 + m]);
  short* od = partO + ((size_t)z * MTOT + qrow0 + r) * DV + c0;
  *(s16x8*)(od) = o0;
  *(s16x8*)(od + 8) = o1;
}

// ---------------------------------------------------------------------------
// Combine: out[row][dv] = sum_z O / (0.8 * sum_z Z[row]).  4 f32 per thread.
// ---------------------------------------------------------------------------
__global__ __launch_bounds__(256) void combine_kernel(
    const short* __restrict__ partO, const float* __restrict__ partZ,
    float* __restrict__ out) {
  const int i = blockIdx.x * 256 + threadIdx.x;  // groups of 4 f32
  const int row = i >> 4, col0 = (i & 15) * 4;
  f32x4 acc = (f32x4){0.f, 0.f, 0.f, 0.f};
  float zf = 0.f;
#pragma unroll
  for (int z = 0; z < KSPLIT; ++z) {
    const s16x4 p = *(const s16x4*)(partO + (((size_t)z * MTOT + row) << 6) + col0);
#pragma unroll
    for (int m = 0; m < 4; ++m) acc[m] += bf2f(p[m]);
    zf += partZ[(size_t)z * MTOT + row];
  }
  const float inv = 1.0f / (0.8f * zf);
  *(f32x4*)(out + (size_t)i * 4) = acc * inv;
}

// ---------------------------------------------------------------------------
extern "C" void kernel_launch(void* const* d_in, const int* in_sizes, int n_in,
                              void* d_out, int out_size, void* d_ws, size_t ws_size,
                              hipStream_t stream) {
  const float* q  = (const float*)d_in[0];
  const float* k  = (const float*)d_in[1];
  const float* v  = (const float*)d_in[2];
  const float* Wq = (const float*)d_in[3];
  const float* bq = (const float*)d_in[4];
  const float* Wk = (const float*)d_in[5];
  const float* bk = (const float*)d_in[6];
  const float* Wv = (const float*)d_in[7];
  const float* bv = (const float*)d_in[8];
  float* out = (float*)d_out;

  // ws: qp 8.4 | kp 8.4 | vpT 2.1 | partO(bf16) 16.8 | partZ 0.5 | W bufs ~0.2
  short* qp  = (short*)d_ws;
  short* kpb = qp + (size_t)MTOT * DM;
  short* vpT = kpb + (size_t)MTOT * DM;
  short* partO = vpT + (size_t)MTOT * DV;
  float* partZ = (float*)(partO + (size_t)KSPLIT * MTOT * DV);
  short* wqT = (short*)(partZ + (size_t)KSPLIT * MTOT);
  short* wkT = wqT + 256 * 256;
  short* wvT = wkT + 32 * 256;
  float* bqs = (float*)(wvT + 64 * 256);

  prep_kernel<<<256, 256, 0, stream>>>(Wq, bq, Wk, Wv, wqT, wkT, wvT, bqs);
  proj_all_kernel<<<2304, 256, 0, stream>>>(q, k, v, wqT, wkT, wvT,
                                            bqs, bk, bv, qp, kpb, vpT);
  attn_kernel<<<2048, 256, 0, stream>>>(qp, kpb, vpT, partO, partZ);
  combine_kernel<<<MTOT * DV / 1024, 256, 0, stream>>>(partO, partZ, out);
}